// Round 1
// baseline (517.837 us; speedup 1.0000x reference)
//
#include <hip/hip_runtime.h>
#include <hip/hip_bf16.h>

typedef unsigned short ushort_t;
typedef _Float16 h2 __attribute__((ext_vector_type(2)));
typedef _Float16 half4_t __attribute__((ext_vector_type(4)));
typedef _Float16 half8_t __attribute__((ext_vector_type(8)));
typedef float f32x4 __attribute__((ext_vector_type(4)));
#define EPSQ 1e-8f

__device__ __forceinline__ float fdot2f(h2 a, h2 b, float c) {
#if __has_builtin(__builtin_amdgcn_fdot2)
  return __builtin_amdgcn_fdot2(a, b, c, false);
#else
  return fmaf((float)a.x, (float)b.x, fmaf((float)a.y, (float)b.y, c));
#endif
}
__device__ __forceinline__ h2 bc_h2(unsigned int v) { return __builtin_bit_cast(h2, v); }
__device__ __forceinline__ unsigned int bc_u32(h2 v) { return __builtin_bit_cast(unsigned int, v); }
__device__ __forceinline__ ushort_t bc_u16(_Float16 v) { return __builtin_bit_cast(ushort_t, v); }

// ws layout (bytes):
//   wc16  [9][64][128] fp16 : off 0        size 147456   (conv1 weights, K-chunked)
//   pwB16 [64][160]    fp16 : off 147456   size 20480    (pconv weights, kk=k*48+ci)
//   Wh    [245760]     fp16 : off 167936   size 491520   (routing W)
//   u16   [4096][384][8] fp16: off 659456  size 25165824
// total ~25.8 MB

// ---------------- K0: weight prep ----------------
__global__ __launch_bounds__(256) void k0_prep(
    const float* __restrict__ w1, const float* __restrict__ pw,
    const float* __restrict__ Wf,
    _Float16* __restrict__ wc16, _Float16* __restrict__ pwB16,
    _Float16* __restrict__ Wh)
{
  int i = blockIdx.x * 256 + threadIdx.x;   // grid 960*256 = 245760
  if (i < 73728) {
    int c  = i / 8192;
    int r  = i % 8192;
    int co = r >> 7;
    int k  = r & 127;
    wc16[i] = (co < 50) ? (_Float16)w1[co*1152 + k*9 + c] : (_Float16)0.f;
  }
  if (i < 10240) {
    int co2 = i / 160, kk = i % 160;
    int k = kk / 48, ci = kk % 48;
    float v = (k < 3 && ci < 42) ? pw[co2*126 + ci*3 + k] : 0.f;
    pwB16[i] = (_Float16)v;
  }
  Wh[i] = (_Float16)Wf[i];
}

// ---------------- K12: MFMA conv1 + relu + MFMA pconv + squash (3 b per block) ----------------
__global__ __launch_bounds__(256) void k12_mfma(
    const float* __restrict__ x, const float* __restrict__ b1,
    const float* __restrict__ b2, const _Float16* __restrict__ wc16,
    const _Float16* __restrict__ pwB16, ushort_t* __restrict__ u16)
{
  __shared__ float smem[19728];
  _Float16* xh   = (_Float16*)smem;
  _Float16* hr16 = (_Float16*)smem;
  _Float16* pB   = (_Float16*)smem + 8736;
  float*    pbuf = smem + 9744;

  const int tid   = threadIdx.x;
  const int w     = tid >> 6;
  const int lane  = tid & 63;
  const int lc    = lane & 15;
  const int qd    = lane >> 4;
  const int gbase = blockIdx.x * 3;

  // ---- stage x: fp32 -> fp16 into padded rows ----
  for (int j = tid; j < 4800; j += 256) {
    int g = j / 1600, r = j - g*1600;
    int p = r >> 5, q = r & 31;
    int bb = gbase + g; if (bb > 4095) bb = 4095;
    float4 v = *(const float4*)(x + bb*6400 + p*128 + q*4);
    half4_t hv = {(_Float16)v.x, (_Float16)v.y, (_Float16)v.z, (_Float16)v.w};
    *(half4_t*)(xh + g*6800 + p*136 + q*4) = hv;
  }
  // ---- stage w chunk 0 into Bbuf0 ----
  {
    const uint4* wg = (const uint4*)wc16;
    uint4* dst = (uint4*)(xh + 20400);
#pragma unroll
    for (int it = 0; it < 4; ++it) {
      int f = it*256 + tid;
      dst[(f >> 4)*17 + (f & 15)] = wg[f];
    }
  }

  const _Float16* abase[2];
#pragma unroll
  for (int tm = 0; tm < 2; ++tm) {
    int m = 32*w + 16*tm + lc;
    if (m > 125) m = 125;
    int g = m / 42, l = m - g*42;
    abase[tm] = xh + g*6800 + l*136 + qd*8;
  }

  f32x4 acc[2][4];
#pragma unroll
  for (int tm = 0; tm < 2; ++tm)
#pragma unroll
    for (int tn = 0; tn < 4; ++tn)
      acc[tm][tn] = (f32x4){0.f, 0.f, 0.f, 0.f};

  __syncthreads();

  uint4 pf[4];
  for (int c = 0; c < 9; ++c) {
    if (c < 8) {
      const uint4* wg = (const uint4*)wc16 + (c + 1)*1024;
#pragma unroll
      for (int it = 0; it < 4; ++it) pf[it] = wg[it*256 + tid];
    }
    const _Float16* Bb = xh + 20400 + (c & 1)*8704;
    const _Float16* a0 = abase[0] + c*136;
    const _Float16* a1 = abase[1] + c*136;
#pragma unroll
    for (int kk = 0; kk < 128; kk += 32) {
      half8_t av0 = *(const half8_t*)(a0 + kk);
      half8_t av1 = *(const half8_t*)(a1 + kk);
#pragma unroll
      for (int tn = 0; tn < 4; ++tn) {
        half8_t bv = *(const half8_t*)(Bb + (16*tn + lc)*136 + qd*8 + kk);
        acc[0][tn] = __builtin_amdgcn_mfma_f32_16x16x32_f16(av0, bv, acc[0][tn], 0, 0, 0);
        acc[1][tn] = __builtin_amdgcn_mfma_f32_16x16x32_f16(av1, bv, acc[1][tn], 0, 0, 0);
      }
    }
    __syncthreads();
    if (c < 8) {
      uint4* dst = (uint4*)(xh + 20400 + ((c + 1) & 1)*8704);
#pragma unroll
      for (int it = 0; it < 4; ++it) {
        int f = it*256 + tid;
        dst[(f >> 4)*17 + (f & 15)] = pf[it];
      }
      __syncthreads();
    }
  }

  // ---- zero hr16 and stage pconv weights ----
  for (int j = tid; j < 4368; j += 256) smem[j] = 0.f;
  {
    const uint4* pg = (const uint4*)pwB16;
    uint4* dst = (uint4*)pB;
    for (int f = tid; f < 1280; f += 256) {
      int row = f / 20, cc = f - row*20;
      dst[row*21 + cc] = pg[f];
    }
  }
  __syncthreads();

  // ---- conv1 epilogue: bias+relu -> hr16[g][co][l] fp16 ----
#pragma unroll
  for (int tm = 0; tm < 2; ++tm) {
    int mb = 32*w + 16*tm + 4*qd;
#pragma unroll
    for (int tn = 0; tn < 4; ++tn) {
      int co = 16*tn + lc;
      if (co < 50) {
        float bias = b1[co];
#pragma unroll
        for (int r = 0; r < 4; ++r) {
          int m = mb + r;
          if (m < 126) {
            int g = m / 42, l = m - g*42;
            hr16[g*2912 + co*56 + l] = (_Float16)fmaxf(acc[tm][tn][r] + bias, 0.f);
          }
        }
      }
    }
  }
  __syncthreads();

  // ---- pconv MFMA: M=144, N=64, K=160 ----
  f32x4 acc2[3][4];
#pragma unroll
  for (int tm = 0; tm < 3; ++tm)
#pragma unroll
    for (int tn = 0; tn < 4; ++tn)
      acc2[tm][tn] = (f32x4){0.f, 0.f, 0.f, 0.f};

#pragma unroll
  for (int kc = 0; kc < 5; ++kc) {
    int kk0 = kc*32 + qd*8;
    int k   = (kk0 >= 144) ? 3 : (kk0 >= 96) ? 2 : (kk0 >= 48) ? 1 : 0;
    int ci0 = kk0 - k*48;
    half8_t bv[4];
#pragma unroll
    for (int tn = 0; tn < 4; ++tn)
      bv[tn] = *(const half8_t*)(pB + (16*tn + lc)*168 + kk0);
#pragma unroll
    for (int tm = 0; tm < 3; ++tm) {
      int T = w + 4*tm; int Tc = (T < 9) ? T : 8;
      int g = Tc/3, l2 = (Tc - g*3)*16 + lc;
      half8_t av = *(const half8_t*)(hr16 + g*2912 + (l2 + k)*56 + ci0);
#pragma unroll
      for (int tn = 0; tn < 4; ++tn)
        acc2[tm][tn] = __builtin_amdgcn_mfma_f32_16x16x32_f16(av, bv[tn], acc2[tm][tn], 0, 0, 0);
    }
  }

  // ---- pconv epilogue -> pbuf[g][co2][l2] ----
#pragma unroll
  for (int tm = 0; tm < 3; ++tm) {
    int T = w + 4*tm;
    if (T < 9) {
      int g = T/3, l2b = (T - g*3)*16;
#pragma unroll
      for (int tn = 0; tn < 4; ++tn) {
        int co2 = 16*tn + lc;
        float bias2 = b2[co2];
#pragma unroll
        for (int r = 0; r < 4; ++r) {
          int l2 = l2b + 4*qd + r;
          pbuf[g*3328 + co2*52 + l2] = acc2[tm][tn][r] + bias2;
        }
      }
    }
  }
  __syncthreads();

  // ---- squash all 3 g -> u16 (fp16) ----
  for (int idx = tid; idx < 1152; idx += 256) {
    int g = idx / 384, cap = idx - g*384;
    int bb = gbase + g;
    if (bb < 4096) {
      int co2 = cap / 6, gg = cap - co2*6;
      const float* pp = pbuf + g*3328 + co2*52 + gg*8;
      float4 a0 = *(const float4*)pp;
      float4 a1 = *(const float4*)(pp + 4);
      float sq = a0.x*a0.x + a0.y*a0.y + a0.z*a0.z + a0.w*a0.w
               + a1.x*a1.x + a1.y*a1.y + a1.z*a1.z + a1.w*a1.w;
      float sc = sq / ((1.f + sq) * (sqrtf(sq) + EPSQ));
      h2 p0 = {(_Float16)(a0.x*sc), (_Float16)(a0.y*sc)};
      h2 p1 = {(_Float16)(a0.z*sc), (_Float16)(a0.w*sc)};
      h2 p2 = {(_Float16)(a1.x*sc), (_Float16)(a1.y*sc)};
      h2 p3 = {(_Float16)(a1.z*sc), (_Float16)(a1.w*sc)};
      *(uint4*)(u16 + ((size_t)bb*384 + cap)*8) =
          make_uint4(bc_u32(p0), bc_u32(p1), bc_u32(p2), bc_u32(p3));
    }
  }
}

// ---------------- K3: u_hat + routing. NB=1 b per block, all-fp16 LDS, fdot2 ----------------
// R8 (this round): NB=2 needed uh16[2][80][416] = 130 KiB LDS -> 1 block/CU,
// OccupancyPercent 16.8, VALUBusy 20%, HBM 1% -> pure latency-bound.
// NB=1 halves LDS to ~71 KiB -> 2 blocks/CU (12 waves), uhreg 80->40 VGPRs.
// Cost accepted: W (480 KB, L2-resident) is read by 2x blocks (+~29 us L2 floor),
// expected to hide under the doubled TLP.
__global__ __launch_bounds__(384) void k3_route(
    const ushort_t* __restrict__ u16, const _Float16* __restrict__ Wh,
    float* __restrict__ out)
{
  __shared__ __align__(16) ushort_t uh16[80][416];
  __shared__ __align__(16) ushort_t coc16[5][416];
  __shared__ __align__(16) ushort_t svh16[80];
  __shared__ float sv[80];
  __shared__ float ff[5];

  const int t  = threadIdx.x;
  const int b  = blockIdx.x;           // grid 4096, one batch per block
  const int q  = t / 96;
  const int jc = t - q*96;
  const int ch = q*104 + jc;

  // load u (fp16) for this batch; thread t owns capsule c = t
  uint4 uu0 = *(const uint4*)(u16 + ((size_t)b*384 + t)*8);
  h2 ua0[4] = {bc_h2(uu0.x), bc_h2(uu0.y), bc_h2(uu0.z), bc_h2(uu0.w)};

  // ---- W-phase: u_hat; uhreg packed half2 (40 VGPRs) ----
  h2 uhreg[40];
#pragma unroll
  for (int o = 0; o < 5; ++o) {
    const uint4* wp = (const uint4*)(Wh + ((size_t)o*384 + t)*128);
#pragma unroll
    for (int dd = 0; dd < 8; ++dd) {
      uint4 w0 = wp[2*dd], w1 = wp[2*dd + 1];
      float s00 = fdot2f(bc_h2(w0.x), ua0[0], fdot2f(bc_h2(w0.y), ua0[1],
                  fdot2f(bc_h2(w0.z), ua0[2], fdot2f(bc_h2(w0.w), ua0[3], 0.f))));
      float s10 = fdot2f(bc_h2(w1.x), ua0[0], fdot2f(bc_h2(w1.y), ua0[1],
                  fdot2f(bc_h2(w1.z), ua0[2], fdot2f(bc_h2(w1.w), ua0[3], 0.f))));
      _Float16 f00 = (_Float16)s00, f10 = (_Float16)s10;
      uh16[o*16 + 2*dd][ch]     = bc_u16(f00);
      uh16[o*16 + 2*dd + 1][ch] = bc_u16(f10);
      uhreg[o*8 + dd] = (h2){f00, f10};
    }
  }

  float lg[5] = {0.f, 0.f, 0.f, 0.f, 0.f};

  for (int it = 0; it < 3; ++it) {
    // softmax over o per c -> coc16 fp16
    {
      float m = fmaxf(fmaxf(fmaxf(lg[0],lg[1]),fmaxf(lg[2],lg[3])),lg[4]);
      float e[5]; float Z = 0.f;
#pragma unroll
      for (int o = 0; o < 5; ++o) { e[o] = __expf(lg[o]-m); Z += e[o]; }
      float inv = 1.f / Z;
#pragma unroll
      for (int o = 0; o < 5; ++o) {
        _Float16 hc = (_Float16)(e[o]*inv);
        coc16[o][ch] = bc_u16(hc);
      }
    }
    __syncthreads();

    // s-phase: thread (od,qq) dots a 96-c strip (uh from LDS)
    if (t < 320) {
      int od = t >> 2, qq = t & 3, o = od >> 4;
      const uint4* ua = (const uint4*)&uh16[od][qq*104];
      const uint4* ca = (const uint4*)&coc16[o][qq*104];
      float sum = 0.f;
#pragma unroll
      for (int j = 0; j < 12; ++j) {
        uint4 uv = ua[j];
        uint4 cv = ca[j];
        sum = fdot2f(bc_h2(uv.x), bc_h2(cv.x), sum);
        sum = fdot2f(bc_h2(uv.y), bc_h2(cv.y), sum);
        sum = fdot2f(bc_h2(uv.z), bc_h2(cv.z), sum);
        sum = fdot2f(bc_h2(uv.w), bc_h2(cv.w), sum);
      }
      sum += __shfl_xor(sum, 1);
      sum += __shfl_xor(sum, 2);
      if (qq == 0) sv[od] = sum;
    }
    __syncthreads();

    // squash factor per o; also emit svh16 = fp16(sv*f) for the uv-phase
    if (t < 5) {
      int o = t;
      float sq = 0.f;
#pragma unroll
      for (int d = 0; d < 16; ++d) { float v = sv[o*16+d]; sq = fmaf(v, v, sq); }
      float f = sq / ((1.f + sq) * (sqrtf(sq) + EPSQ));
      ff[o] = f;
      if (it < 2) {
#pragma unroll
        for (int d = 0; d < 16; ++d) {
          _Float16 hf = (_Float16)(sv[o*16+d] * f);
          svh16[o*16+d] = bc_u16(hf);
        }
      }
    }
    __syncthreads();

    if (it == 2) {
      if (t < 80) {
        out[(size_t)b*80 + t] = sv[t] * ff[t >> 4];
      }
    } else {
      // logits update: dv = <tu, v> via packed fdot2 from registers + svh16
#pragma unroll
      for (int o = 0; o < 5; ++o) {
        uint4 s0 = *(const uint4*)&svh16[o*16];
        uint4 s1 = *(const uint4*)&svh16[o*16 + 8];
        float dv = 0.f;
        dv = fdot2f(uhreg[o*8+0], bc_h2(s0.x), dv);
        dv = fdot2f(uhreg[o*8+1], bc_h2(s0.y), dv);
        dv = fdot2f(uhreg[o*8+2], bc_h2(s0.z), dv);
        dv = fdot2f(uhreg[o*8+3], bc_h2(s0.w), dv);
        dv = fdot2f(uhreg[o*8+4], bc_h2(s1.x), dv);
        dv = fdot2f(uhreg[o*8+5], bc_h2(s1.y), dv);
        dv = fdot2f(uhreg[o*8+6], bc_h2(s1.z), dv);
        dv = fdot2f(uhreg[o*8+7], bc_h2(s1.w), dv);
        lg[o] += dv;
      }
    }
  }
}

extern "C" void kernel_launch(void* const* d_in, const int* in_sizes, int n_in,
                              void* d_out, int out_size, void* d_ws, size_t ws_size,
                              hipStream_t stream) {
  const float* x  = (const float*)d_in[0];
  const float* w1 = (const float*)d_in[1];
  const float* b1 = (const float*)d_in[2];
  const float* pw = (const float*)d_in[3];
  const float* b2 = (const float*)d_in[4];
  const float* Wf = (const float*)d_in[5];
  float* out = (float*)d_out;
  char* ws = (char*)d_ws;

  _Float16* wc16  = (_Float16*)(ws);
  _Float16* pwB16 = (_Float16*)(ws + 147456);
  _Float16* Wh    = (_Float16*)(ws + 167936);
  ushort_t* u16   = (ushort_t*)(ws + 659456);

  k0_prep<<<960, 256, 0, stream>>>(w1, pw, Wf, wc16, pwB16, Wh);
  k12_mfma<<<1366, 256, 0, stream>>>(x, b1, b2, wc16, pwB16, u16);
  k3_route<<<4096, 384, 0, stream>>>(u16, Wh, out);
}